// Round 15
// baseline (86.821 us; speedup 1.0000x reference)
//
#include <hip/hip_runtime.h>
#include <hip/hip_fp16.h>
#include <stdint.h>

#define N_NODES   4096
#define N_EDGES   128
#define D_X       128
#define PE_DIM    64
#define NUM_WALKS 10
#define N_WALKS_TOT (N_NODES * NUM_WALKS)   /* 40960 */
#define OUT_COLS  (D_X + PE_DIM)            /* 192 */
#define ROW_CAP   512u                      /* adjacency row stride (u16) */
#define VCAP      512u                      /* visitor list cap (max expected ~180) */
#define EMCAP     256                       /* edge member cap (max expected ~110) */

/* workspace layout (bytes) — ~13.2 MiB */
#define OFF_MASKS   0u                                    /* 64 KiB */
#define OFF_DEG     (OFF_MASKS + N_NODES * 16u)           /* 16 KiB */
#define OFF_ADJ     (OFF_DEG + N_NODES * 4u)              /* 4 MiB */
#define OFF_WM      (OFF_ADJ + N_NODES * ROW_CAP * 2u)    /* 5 MiB */
#define OFF_VCNT    (OFF_WM + (size_t)N_WALKS_TOT * PE_DIM * 2u) /* 16 KiB */
#define OFF_VLIST   (OFF_VCNT + N_NODES * 4u)             /* 4 MiB */

/* edge membership tables in .bss: zero at load; k_gather re-zeroes g_ecnt
   for the NEXT launch => invariant ecnt==0 at every launch entry. */
__device__ unsigned int   g_ecnt[N_EDGES];
__device__ unsigned short g_emem[N_EDGES * EMCAP];

/* ---- threefry2x32 (20 rounds) — cheap high-quality PRF ---- */
__device__ __forceinline__ void tf2x32(uint32_t kk0, uint32_t kk1,
                                       uint32_t x0, uint32_t x1,
                                       uint32_t& o0, uint32_t& o1) {
  const uint32_t kk2 = kk0 ^ kk1 ^ 0x1BD11BDAu;
  x0 += kk0; x1 += kk1;
  auto rnd = [&](int r) {
    x0 += x1;
    x1 = (x1 << r) | (x1 >> (32 - r));
    x1 ^= x0;
  };
  rnd(13); rnd(15); rnd(26); rnd(6);   x0 += kk1; x1 += kk2 + 1u;
  rnd(17); rnd(29); rnd(16); rnd(24);  x0 += kk2; x1 += kk0 + 2u;
  rnd(13); rnd(15); rnd(26); rnd(6);   x0 += kk0; x1 += kk1 + 3u;
  rnd(17); rnd(29); rnd(16); rnd(24);  x0 += kk1; x1 += kk2 + 4u;
  rnd(13); rnd(15); rnd(26); rnd(6);   x0 += kk2; x1 += kk0 + 5u;
  o0 = x0; o1 = x1;
}

/* ---- K1: node masks + edge member lists + vcnt zero (one wave/node) ---- */
__global__ void k_build(const float* __restrict__ inc,
                        ulonglong2* __restrict__ masks,
                        unsigned int* __restrict__ vcnt) {
  const int wid = threadIdx.x >> 6, lane = threadIdx.x & 63;
  const int i = blockIdx.x * 4 + wid;
  const float a = inc[i * N_EDGES + lane];        /* edge lane    */
  const float b = inc[i * N_EDGES + 64 + lane];   /* edge 64+lane */
  const unsigned long long m0 = __ballot(a != 0.f);
  const unsigned long long m1 = __ballot(b != 0.f);
  if (lane == 0) {
    masks[i] = make_ulonglong2(m0, m1);
    vcnt[i] = 0u;
  }
  if (a != 0.f) {
    const unsigned int s = atomicAdd(&g_ecnt[lane], 1u);
    if (s < EMCAP) g_emem[(lane << 8) + s] = (unsigned short)i;
  }
  if (b != 0.f) {
    const unsigned int s = atomicAdd(&g_ecnt[64 + lane], 1u);
    if (s < EMCAP) g_emem[((64 + lane) << 8) + s] = (unsigned short)i;
  }
}

/* ---- K2: adjacency row per WAVE via edge-member streaming + LDS bitmap
   dedupe + prefix-compact. Produces the SAME ascending 512-capped rows as
   the old all-pairs kernel at ~1/13 the work. ---- */
__global__ void __launch_bounds__(256)
k_adjb(const ulonglong2* __restrict__ masks,
       unsigned short* __restrict__ adj, unsigned int* __restrict__ deg) {
  __shared__ unsigned int bm[4][N_NODES / 32];   /* 4 waves x 512 B */
  const int wid = threadIdx.x >> 6, lane = threadIdx.x & 63;
  const int i = blockIdx.x * 4 + wid;
  unsigned int* b = bm[wid];
  b[lane] = 0u;
  b[64 + lane] = 0u;
  __syncthreads();

  const ulonglong2 mi = masks[i];                /* wave-uniform */
  unsigned long long mm0 = mi.x, mm1 = mi.y;
  while (mm0) {
    const int e = __ffsll(mm0) - 1; mm0 &= mm0 - 1;
    unsigned int cnt = g_ecnt[e]; if (cnt > EMCAP) cnt = EMCAP;
    for (unsigned int s = lane; s < cnt; s += 64) {
      const unsigned int nb = g_emem[(e << 8) + s];
      if (nb != (unsigned int)i) atomicOr(&b[nb >> 5], 1u << (nb & 31));
    }
  }
  while (mm1) {
    const int e = 64 + __ffsll(mm1) - 1; mm1 &= mm1 - 1;
    unsigned int cnt = g_ecnt[e]; if (cnt > EMCAP) cnt = EMCAP;
    for (unsigned int s = lane; s < cnt; s += 64) {
      const unsigned int nb = g_emem[(e << 8) + s];
      if (nb != (unsigned int)i) atomicOr(&b[nb >> 5], 1u << (nb & 31));
    }
  }
  __syncthreads();                               /* all LDS atomics done */

  /* compact: lane owns words 2*lane, 2*lane+1 (nodes lane*64..lane*64+63) */
  const unsigned int w0 = b[2 * lane], w1 = b[2 * lane + 1];
  const unsigned int pc = __popc(w0) + __popc(w1);
  unsigned int pre = pc;
#pragma unroll
  for (int d = 1; d < 64; d <<= 1) {
    const unsigned int t = __shfl_up(pre, d);
    if (lane >= d) pre += t;
  }
  const unsigned int total = __shfl(pre, 63);
  pre -= pc;                                     /* exclusive prefix */
  unsigned short* row = adj + ((unsigned int)i << 9);
  unsigned int pos = pre;
  unsigned int t0 = w0;
  while (t0) {
    const int bit = __ffs(t0) - 1; t0 &= t0 - 1;
    if (pos < ROW_CAP) row[pos] = (unsigned short)(lane * 64 + bit);
    ++pos;
  }
  unsigned int t1 = w1;
  while (t1) {
    const int bit = __ffs(t1) - 1; t1 &= t1 - 1;
    if (pos < ROW_CAP) row[pos] = (unsigned short)(lane * 64 + 32 + bit);
    ++pos;
  }
  if (lane == 63) deg[i] = (total < ROW_CAP) ? total : ROW_CAP;
}

/* ---- K3: walks (1 uniform draw/step) + mean embed + visit records ----
   Wave per walk; symmetric graph => full-length or length-1. (R7 verbatim) */
__global__ void __launch_bounds__(256)
k_walk(const unsigned int* __restrict__ deg,
       const unsigned short* __restrict__ adj,
       const float* __restrict__ embed,
       __half* __restrict__ walk_m,
       unsigned int* __restrict__ vcnt, unsigned short* __restrict__ vlist) {
  const int wid = threadIdx.x >> 6, lane = threadIdx.x & 63;
  const int w = blockIdx.x * 4 + wid;

  uint32_t a0, a1;
  tf2x32(0u, 42u, (uint32_t)w, (uint32_t)(lane & 1), a0, a1);
  const uint32_t rnd0 = __shfl(a0, 0);
  const uint32_t rnd1 = __shfl(a1, 0);
  const uint32_t rnd2 = __shfl(a0, 1);
  const uint32_t rnd3 = __shfl(a1, 1);

  const uint32_t n0 = (uint32_t)w / NUM_WALKS;
  uint32_t n1, n2, n3, n4, nvalid;
  const unsigned int d0 = deg[n0];
  if (d0 == 0) {
    n1 = n2 = n3 = n4 = n0;
    nvalid = 1u;
  } else {
    uint32_t cur = n0;
    unsigned int d;
    cur = adj[(cur << 9) + (uint32_t)(((uint64_t)rnd0 * d0) >> 32)]; n1 = cur;
    d = deg[cur];
    cur = adj[(cur << 9) + (uint32_t)(((uint64_t)rnd1 * d) >> 32)]; n2 = cur;
    d = deg[cur];
    cur = adj[(cur << 9) + (uint32_t)(((uint64_t)rnd2 * d) >> 32)]; n3 = cur;
    d = deg[cur];
    cur = adj[(cur << 9) + (uint32_t)(((uint64_t)rnd3 * d) >> 32)]; n4 = cur;
    nvalid = 5u;
  }

  float s = embed[n0 * PE_DIM + lane];
  if (nvalid == 5u) {
    s += embed[n1 * PE_DIM + lane];
    s += embed[n2 * PE_DIM + lane];
    s += embed[n3 * PE_DIM + lane];
    s += embed[n4 * PE_DIM + lane];
  }
  const float m = s / (float)nvalid;

  walk_m[(size_t)w * PE_DIM + lane] = __float2half(m);

  if ((unsigned int)lane < nvalid) {
    uint32_t node = n0;
    if (lane == 1) node = n1;
    if (lane == 2) node = n2;
    if (lane == 3) node = n3;
    if (lane == 4) node = n4;
    const unsigned int slot = atomicAdd(&vcnt[node], 1u);
    if (slot < VCAP) vlist[node * VCAP + slot] = (unsigned short)w;
  }
}

/* ---- K4: block per node; 4 waves x 8-deep ILP gather of visitor means;
   x passthrough on wave 3; re-zero g_ecnt for next launch. (R7 + rezero) */
__global__ void __launch_bounds__(256)
k_gather(const __half* __restrict__ walk_m,
         const unsigned int* __restrict__ vcnt,
         const unsigned short* __restrict__ vlist,
         const float* __restrict__ x,
         float* __restrict__ out) {
  __shared__ float red[4][PE_DIM];
  const int wid = threadIdx.x >> 6, lane = threadIdx.x & 63;
  const int v = blockIdx.x;

  if (v == 0 && threadIdx.x < N_EDGES) g_ecnt[threadIdx.x] = 0u;

  if (wid == 3) {
    const float2 xv = ((const float2*)(x + (size_t)v * D_X))[lane];
    ((float2*)(out + (size_t)v * OUT_COLS))[lane] = xv;
  }

  unsigned int c = vcnt[v];
  if (c > VCAP) c = VCAP;
  const unsigned short* vl = vlist + (unsigned int)v * VCAP;

  float s = 0.f;
  for (unsigned int base = (unsigned int)wid * 8u; base < c; base += 32u) {
#pragma unroll
    for (int q = 0; q < 8; ++q) {
      const unsigned int idx = base + (unsigned int)q;
      const bool ok = idx < c;
      const unsigned int ww = ok ? (unsigned int)vl[idx] : (unsigned int)vl[0];
      const float val = __half2float(walk_m[(size_t)ww * PE_DIM + lane]);
      s += ok ? val : 0.f;
    }
  }
  red[wid][lane] = s;
  __syncthreads();
  if (wid == 0) {
    const float t = red[0][lane] + red[1][lane] + red[2][lane] + red[3][lane];
    out[(size_t)v * OUT_COLS + D_X + lane] = c ? t / (float)c : 0.f;
  }
}

extern "C" void kernel_launch(void* const* d_in, const int* in_sizes, int n_in,
                              void* d_out, int out_size, void* d_ws, size_t ws_size,
                              hipStream_t stream) {
  const float* x   = (const float*)d_in[0];
  const float* inc = (const float*)d_in[1];
  const float* emb = (const float*)d_in[2];
  float* out = (float*)d_out;

  char* ws = (char*)d_ws;
  ulonglong2*     masks = (ulonglong2*)(ws + OFF_MASKS);
  unsigned int*   deg   = (unsigned int*)(ws + OFF_DEG);
  unsigned short* adj   = (unsigned short*)(ws + OFF_ADJ);
  __half*         wm    = (__half*)(ws + OFF_WM);
  unsigned int*   vcnt  = (unsigned int*)(ws + OFF_VCNT);
  unsigned short* vlist = (unsigned short*)(ws + OFF_VLIST);

  k_build <<<N_NODES / 4, 256, 0, stream>>>(inc, masks, vcnt);
  k_adjb  <<<N_NODES / 4, 256, 0, stream>>>(masks, adj, deg);
  k_walk  <<<N_WALKS_TOT / 4, 256, 0, stream>>>(deg, adj, emb, wm, vcnt, vlist);
  k_gather<<<N_NODES, 256, 0, stream>>>(wm, vcnt, vlist, x, out);
}